// Round 16
// baseline (23.738 us; speedup 1.0000x reference)
//
#include <hip/hip_runtime.h>
#include <hip/hip_bf16.h>

// Guided attention loss, two-kernel. r16 = r13 with ROWS_PER_WAVE 8 -> 16.
//   guided(b,x,y) = 1 - exp(-(y/il - x/ol)^2 / (2*sigma^2)),  sigma=0.4
//   out[b]   = sum(guided*att over valid) / ol
//   out[B+b] = sum((guided*att)^2 over valid) / ol
// Shapes fixed: B=64, T_out=2048, T_in=512.
//
// Round 16 (ONE change vs r13): each wave owns 16 rows (4 groups x q-row),
// 32 float4 loads up-front. Halves live-wave count (8192 -> 4096) so the
// per-wave exposed HBM latency (the ~12us of k1 not explained by issue
// cycles) is paid half as often. __launch_bounds__(64,3) keeps the 128
// data-VGPRs from spilling. k1 effective BW so far pinned at 4.4 TB/s
// across 3 structures; this is the wave-turnover test.

#define GA_B     64
#define GA_TOUT  2048
#define GA_TIN   512
#define ROWS_PER_WAVE   16
#define NGROUP          4                            // 4-row groups per wave
#define NCHUNK          (GA_TOUT / ROWS_PER_WAVE)    // 128 chunks per batch
// KS = sqrt(3.125 * log2(e)):  2^(-(KS*z)^2) = exp(-z^2 * 3.125)
#define KS 2.1233046f

__global__ __launch_bounds__(64, 3)
void ga_partial_kernel(const float* __restrict__ att,
                       const int* __restrict__ ilens,
                       const int* __restrict__ olens,
                       float2* __restrict__ part) {
    const int b       = blockIdx.y;
    const int waveRow = blockIdx.x * ROWS_PER_WAVE;
    const int ol      = olens[b];
    if (waveRow >= ol) return;                   // dead block: k2 won't read it

    const int lane = threadIdx.x;
    const int il   = ilens[b];

    const int q = lane >> 4;                     // row within 4-row group
    const int l = lane & 15;                     // column sub-group
    const int full_w = il >> 6;                  // fully-valid 64-col windows
    const int nw     = (il + 63) >> 6;           // total windows incl. boundary

    const float inv_il_s = KS / (float)il;
    const float inv_ol_s = KS / (float)ol;
    const float* __restrict__ bbase = att + (size_t)b * GA_TOUT * GA_TIN;

    int   row[NGROUP];
    float gx[NGROUP];
    #pragma unroll
    for (int g = 0; g < NGROUP; ++g) {
        row[g] = waveRow + g * 4 + q;
        gx[g]  = (float)row[g] * inv_ol_s;
    }

    float ysb[4];
    #pragma unroll
    for (int j = 0; j < 4; ++j)
        ysb[j] = (float)((l << 2) + j) * inv_il_s;

    // boundary-window (index full_w) column masks
    float mb[4];
    #pragma unroll
    for (int j = 0; j < 4; ++j) {
        const int col = (full_w << 6) + (l << 2) + j;
        mb[j] = (col < il) ? 1.0f : 0.0f;
    }

    // ---- loads: up to 32 float4 issued before compute ----
    float4 A[NGROUP][8];
    #pragma unroll
    for (int w = 0; w < 8; ++w) {
        #pragma unroll
        for (int g = 0; g < NGROUP; ++g) {
            A[g][w] = make_float4(0.f, 0.f, 0.f, 0.f);
            if (w < nw && row[g] < ol) {
                A[g][w] = ((const float4*)(bbase + (size_t)row[g] * GA_TIN))
                          [(w << 4) + l];
            }
        }
    }

    float l1 = 0.0f, l2 = 0.0f;

    // ---- compute: full windows unmasked, boundary window masked ----
    #pragma unroll
    for (int w = 0; w < 8; ++w) {
        if (w < full_w) {                        // wave-uniform: unmasked
            const float off = (float)(w << 6) * inv_il_s;
            #pragma unroll
            for (int g = 0; g < NGROUP; ++g) {
                const float  c = off - gx[g];
                const float4 a = A[g][w];
                #pragma unroll
                for (int j = 0; j < 4; ++j) {
                    const float av = (j == 0) ? a.x : (j == 1) ? a.y
                                   : (j == 2) ? a.z : a.w;
                    const float wv = ysb[j] + c;
                    const float E  = exp2f(-wv * wv);
                    const float e  = av - av * E;
                    l1 += e;
                    l2 += e * e;
                }
            }
        } else if (w < nw) {                     // boundary window: masked
            const float off = (float)(w << 6) * inv_il_s;
            #pragma unroll
            for (int g = 0; g < NGROUP; ++g) {
                const float  c = off - gx[g];
                const float4 a = A[g][w];
                #pragma unroll
                for (int j = 0; j < 4; ++j) {
                    const float av = (j == 0) ? a.x : (j == 1) ? a.y
                                   : (j == 2) ? a.z : a.w;
                    const float wv = ysb[j] + c;
                    const float E  = exp2f(-wv * wv);
                    const float e  = (av - av * E) * mb[j];
                    l1 += e;
                    l2 += e * e;
                }
            }
        }
    }

    // ---- wave reduce (no barrier, no LDS) ----
    #pragma unroll
    for (int o = 32; o > 0; o >>= 1) {
        l1 += __shfl_down(l1, o, 64);
        l2 += __shfl_down(l2, o, 64);
    }
    if (lane == 0)
        part[b * NCHUNK + blockIdx.x] = make_float2(l1, l2);
}

__global__ __launch_bounds__(64)
void ga_final_kernel(const float2* __restrict__ part,
                     const int* __restrict__ olens,
                     float* __restrict__ out) {
    const int b  = blockIdx.x;
    const int t  = threadIdx.x;
    const int ol = olens[b];
    const int nchunks = (ol + ROWS_PER_WAVE - 1) / ROWS_PER_WAVE;  // <= 128
    float l1 = 0.0f, l2 = 0.0f;
    for (int c = t; c < nchunks; c += 64) {
        const float2 p = part[b * NCHUNK + c];
        l1 += p.x; l2 += p.y;
    }
    #pragma unroll
    for (int o = 32; o > 0; o >>= 1) {
        l1 += __shfl_down(l1, o, 64);
        l2 += __shfl_down(l2, o, 64);
    }
    if (t == 0) {
        const float d = (float)ol;
        out[b]        = l1 / d;
        out[GA_B + b] = l2 / d;
    }
}

extern "C" void kernel_launch(void* const* d_in, const int* in_sizes, int n_in,
                              void* d_out, int out_size, void* d_ws, size_t ws_size,
                              hipStream_t stream) {
    const float* att   = (const float*)d_in[0];
    const int*   ilens = (const int*)d_in[1];
    const int*   olens = (const int*)d_in[2];
    float*       out   = (float*)d_out;
    float2*      part  = (float2*)d_ws;   // 64 * 128 * 8 B = 64 KB

    dim3 grid1(NCHUNK, GA_B);
    ga_partial_kernel<<<grid1, 64, 0, stream>>>(att, ilens, olens, part);
    ga_final_kernel<<<GA_B, 64, 0, stream>>>(part, olens, out);
}

// Round 18
// 22.263 us; speedup vs baseline: 1.0663x; 1.0663x over previous
//
#include <hip/hip_runtime.h>
#include <hip/hip_bf16.h>

// Guided attention loss, two-kernel. r18 = r13 verbatim (best: 22.21us).
//   guided(b,x,y) = 1 - exp(-(y/il - x/ol)^2 / (2*sigma^2)),  sigma=0.4
//   out[b]   = sum(guided*att over valid) / ol
//   out[B+b] = sum((guided*att)^2 over valid) / ol
// Shapes fixed: B=64, T_out=2048, T_in=512.
//
// Final structure rationale:
//  - k1 reads only the valid region (window-skip): ~75.5 MB, HBM-cold each
//    replay (harness 1 GiB ws re-poison thrashes L3) -> 12.0us BW floor;
//    measured k1 work ~12.5-13us = 93-96% of roofline.
//  - 1-wave blocks, 8 rows/wave, 16 float4 in flight; dead blocks exit
//    before any memory touch; wave-shuffle reduce (no LDS/barrier).
//  - k2: 64 blocks, reads only live chunks, ~1.5us.
//  - Fusion alternatives all falsified: fence-ticket +120us (r7), contended
//    atomics +9us (r8), cooperative launch silently no-ops under graph
//    capture (r17). Axis swap +3.7us (r14). Bigger waves/blocks: null or
//    worse (r9/r12/r15/r16).

#define GA_B     64
#define GA_TOUT  2048
#define GA_TIN   512
#define ROWS_PER_WAVE   8
#define NCHUNK          (GA_TOUT / ROWS_PER_WAVE)    // 256 chunks per batch
// KS = sqrt(3.125 * log2(e)):  2^(-(KS*z)^2) = exp(-z^2 * 3.125)
#define KS 2.1233046f

__global__ __launch_bounds__(64)
void ga_partial_kernel(const float* __restrict__ att,
                       const int* __restrict__ ilens,
                       const int* __restrict__ olens,
                       float2* __restrict__ part) {
    const int b       = blockIdx.y;
    const int waveRow = blockIdx.x * ROWS_PER_WAVE;
    const int ol      = olens[b];
    if (waveRow >= ol) return;                   // dead block: k2 won't read it

    const int lane = threadIdx.x;
    const int il   = ilens[b];

    const int q = lane >> 4;                     // row within 4-row group
    const int l = lane & 15;                     // column sub-group
    const int full_w = il >> 6;                  // fully-valid 64-col windows
    const int nw     = (il + 63) >> 6;           // total windows incl. boundary

    const float inv_il_s = KS / (float)il;
    const float inv_ol_s = KS / (float)ol;
    const float* __restrict__ bbase = att + (size_t)b * GA_TOUT * GA_TIN;

    int   row[2];
    float gx[2];
    #pragma unroll
    for (int g = 0; g < 2; ++g) {
        row[g] = waveRow + g * 4 + q;
        gx[g]  = (float)row[g] * inv_ol_s;
    }

    float ysb[4];
    #pragma unroll
    for (int j = 0; j < 4; ++j)
        ysb[j] = (float)((l << 2) + j) * inv_il_s;

    // boundary-window (index full_w) column masks
    float mb[4];
    #pragma unroll
    for (int j = 0; j < 4; ++j) {
        const int col = (full_w << 6) + (l << 2) + j;
        mb[j] = (col < il) ? 1.0f : 0.0f;
    }

    // ---- loads: up to 16 float4 issued before compute ----
    float4 A[2][8];
    #pragma unroll
    for (int w = 0; w < 8; ++w) {
        #pragma unroll
        for (int g = 0; g < 2; ++g) {
            A[g][w] = make_float4(0.f, 0.f, 0.f, 0.f);
            if (w < nw && row[g] < ol) {
                A[g][w] = ((const float4*)(bbase + (size_t)row[g] * GA_TIN))
                          [(w << 4) + l];
            }
        }
    }

    float l1 = 0.0f, l2 = 0.0f;

    // ---- compute: full windows unmasked, boundary window masked ----
    #pragma unroll
    for (int w = 0; w < 8; ++w) {
        if (w < full_w) {                        // wave-uniform: unmasked
            const float off = (float)(w << 6) * inv_il_s;
            #pragma unroll
            for (int g = 0; g < 2; ++g) {
                const float  c = off - gx[g];
                const float4 a = A[g][w];
                #pragma unroll
                for (int j = 0; j < 4; ++j) {
                    const float av = (j == 0) ? a.x : (j == 1) ? a.y
                                   : (j == 2) ? a.z : a.w;
                    const float wv = ysb[j] + c;
                    const float E  = exp2f(-wv * wv);
                    const float e  = av - av * E;
                    l1 += e;
                    l2 += e * e;
                }
            }
        } else if (w < nw) {                     // boundary window: masked
            const float off = (float)(w << 6) * inv_il_s;
            #pragma unroll
            for (int g = 0; g < 2; ++g) {
                const float  c = off - gx[g];
                const float4 a = A[g][w];
                #pragma unroll
                for (int j = 0; j < 4; ++j) {
                    const float av = (j == 0) ? a.x : (j == 1) ? a.y
                                   : (j == 2) ? a.z : a.w;
                    const float wv = ysb[j] + c;
                    const float E  = exp2f(-wv * wv);
                    const float e  = (av - av * E) * mb[j];
                    l1 += e;
                    l2 += e * e;
                }
            }
        }
    }

    // ---- wave reduce (no barrier, no LDS) ----
    #pragma unroll
    for (int o = 32; o > 0; o >>= 1) {
        l1 += __shfl_down(l1, o, 64);
        l2 += __shfl_down(l2, o, 64);
    }
    if (lane == 0)
        part[b * NCHUNK + blockIdx.x] = make_float2(l1, l2);
}

__global__ __launch_bounds__(64)
void ga_final_kernel(const float2* __restrict__ part,
                     const int* __restrict__ olens,
                     float* __restrict__ out) {
    const int b  = blockIdx.x;
    const int t  = threadIdx.x;
    const int ol = olens[b];
    const int nchunks = (ol + ROWS_PER_WAVE - 1) >> 3;   // <= 256 live chunks
    float l1 = 0.0f, l2 = 0.0f;
    for (int c = t; c < nchunks; c += 64) {
        const float2 p = part[b * NCHUNK + c];
        l1 += p.x; l2 += p.y;
    }
    #pragma unroll
    for (int o = 32; o > 0; o >>= 1) {
        l1 += __shfl_down(l1, o, 64);
        l2 += __shfl_down(l2, o, 64);
    }
    if (t == 0) {
        const float d = (float)ol;
        out[b]        = l1 / d;
        out[GA_B + b] = l2 / d;
    }
}

extern "C" void kernel_launch(void* const* d_in, const int* in_sizes, int n_in,
                              void* d_out, int out_size, void* d_ws, size_t ws_size,
                              hipStream_t stream) {
    const float* att   = (const float*)d_in[0];
    const int*   ilens = (const int*)d_in[1];
    const int*   olens = (const int*)d_in[2];
    float*       out   = (float*)d_out;
    float2*      part  = (float2*)d_ws;   // 64 * 256 * 8 B = 128 KB

    dim3 grid1(NCHUNK, GA_B);
    ga_partial_kernel<<<grid1, 64, 0, stream>>>(att, ilens, olens, part);
    ga_final_kernel<<<GA_B, 64, 0, stream>>>(part, olens, out);
}